// Round 11
// baseline (29680.673 us; speedup 1.0000x reference)
//
#include <hip/hip_runtime.h>
#include <math.h>

// ---------------------------------------------------------------------------
// DefaultHumanoidGRUCritic on MI355X — round 11
//
// Residency matrix closed: r9 (pin + waves_per_eu(1,1), <=4 waves/WG) is the
// ONLY combo that kept 96 weight floats/lane in VGPRs (VGPR=132). r10's
// fusion won (27.6ms) but its (1,2)/6-wave shape spilled the pinned weights
// to scratch (VGPR=88 < 96) -> ~1.1us/step L2 re-read, serial.
// Round-11 = r10 fusion + r9 allocator recipe:
//   * 128 WGs x 192 thr (3 waves/WG -> waves_per_eu(1,1) feasible -> 512-VGPR
//     budget; pin4 -> resident). 1 WG/CU (96KB pad).
//   * per WG: tid<64 = 4 h0 els x 16 lanes; tid 64-191 = 4 h1 els x 32 lanes
//     (ih|hh halves). 96 weight floats/lane.
//   * staging: batched 16B coherent loads (ld16x2/ld16x3, one vmcnt(0)),
//     <=3 loads/thread, per-8B-half tag verify.
//   * keep: 1 barrier/iter, parity LDS double-buffer, ig prefetch 1 ahead,
//     16-slot rings, no throttle.
// ---------------------------------------------------------------------------

#define T_STEPS 16384
#define IN_DIM 341
#define HID 512
#define G3 1536
#define TTILE 16
#define R0 16
#define R0M (R0-1)
#define R1 16
#define R1M (R1-1)

typedef unsigned int v4u __attribute__((ext_vector_type(4)));

__device__ __forceinline__ float dot4(float4 a, float4 b) {
  return fmaf(a.x, b.x, fmaf(a.y, b.y, fmaf(a.z, b.z, a.w * b.w)));
}
__device__ __forceinline__ float fast_sigmoid(float x) {
  return __builtin_amdgcn_rcpf(1.0f + __expf(-x));
}
__device__ __forceinline__ float fast_tanh(float x) {
  return fmaf(-2.0f, __builtin_amdgcn_rcpf(1.0f + __expf(2.0f * x)), 1.0f);
}
__device__ __forceinline__ void st_rlx64(unsigned long long* p, unsigned long long v) {
  __hip_atomic_store(p, v, __ATOMIC_RELAXED, __HIP_MEMORY_SCOPE_AGENT);
}
__device__ __forceinline__ unsigned long long pack_tv(unsigned tag, float v) {
  return ((unsigned long long)tag << 32) | (unsigned long long)__float_as_uint(v);
}
__device__ __forceinline__ void pin4(float4& v) {
  asm volatile("" : "+v"(v.x), "+v"(v.y), "+v"(v.z), "+v"(v.w));
}
// coherence-point 16B loads; each 8B half is an independently tag-verified
// (val,tag) pair written by an 8B atomic store (torn halves detected+retried).
__device__ __forceinline__ v4u ld16(const unsigned long long* p) {
  v4u r;
  asm volatile("global_load_dwordx4 %0, %1, off sc0 sc1\n\ts_waitcnt vmcnt(0)"
               : "=&v"(r) : "v"(p) : "memory");
  return r;
}
__device__ __forceinline__ void ld16x2(const unsigned long long* p0,
                                       const unsigned long long* p1,
                                       v4u& a, v4u& b) {
  asm volatile("global_load_dwordx4 %0, %2, off sc0 sc1\n\t"
               "global_load_dwordx4 %1, %3, off sc0 sc1\n\t"
               "s_waitcnt vmcnt(0)"
               : "=&v"(a), "=&v"(b) : "v"(p0), "v"(p1) : "memory");
}
__device__ __forceinline__ void ld16x3(const unsigned long long* p0,
                                       const unsigned long long* p1,
                                       const unsigned long long* p2,
                                       v4u& a, v4u& b, v4u& c) {
  asm volatile("global_load_dwordx4 %0, %3, off sc0 sc1\n\t"
               "global_load_dwordx4 %1, %4, off sc0 sc1\n\t"
               "global_load_dwordx4 %2, %5, off sc0 sc1\n\t"
               "s_waitcnt vmcnt(0)"
               : "=&v"(a), "=&v"(b), "=&v"(c)
               : "v"(p0), "v"(p1), "v"(p2) : "memory");
}
__device__ __forceinline__ void vfy(v4u& x, const unsigned long long* p, unsigned want) {
  while (x.y != want || x.w != want) { __builtin_amdgcn_s_sleep(1); x = ld16(p); }
}
__device__ __forceinline__ float2 pairval(v4u x) {
  return make_float2(__uint_as_float(x.x), __uint_as_float(x.z));
}

// ---- k0: concat observations ----------------------------------------------
__global__ __launch_bounds__(384) void concat_kernel(
    const float* __restrict__ p0, const float* __restrict__ p1,
    const float* __restrict__ p2, const float* __restrict__ p3,
    const float* __restrict__ p4, const float* __restrict__ p5,
    const float* __restrict__ p6, const float* __restrict__ p7,
    const float* __restrict__ p8, const float* __restrict__ p9,
    const float* __restrict__ p10, const float* __restrict__ p11,
    const float* __restrict__ p12, float* __restrict__ obs) {
  int t = blockIdx.x;
  int k = threadIdx.x;
  if (k >= IN_DIM) return;
  float v;
  if (k < 21)       v = p0[t*21 + k];
  else if (k < 42)  v = p1[t*21 + (k-21)];
  else if (k < 202) v = p2[t*160 + (k-42)];
  else if (k < 298) v = p3[t*96 + (k-202)];
  else if (k < 301) v = p4[t*3 + (k-298)];
  else if (k < 304) v = p5[t*3 + (k-301)];
  else if (k < 325) v = p6[t*21 + (k-304)];
  else if (k < 328) v = p7[t*3 + (k-325)];
  else if (k < 332) v = p8[t*4 + (k-328)];
  else if (k < 335) v = p9[t*3 + (k-332)];
  else if (k < 338) v = p10[t*3 + (k-335)];
  else if (k < 340) v = p11[t*2 + (k-338)];
  else              v = p12[t];
  obs[(size_t)t*IN_DIM + k] = v;
}

// ---- k1: transpose w_ih0 ---------------------------------------------------
__global__ __launch_bounds__(256) void transpose_kernel(const float* __restrict__ w,
                                                        float* __restrict__ wT) {
  __shared__ float tile[32][33];
  int tx = threadIdx.x;  // 32
  int ty = threadIdx.y;  // 8
  int k = blockIdx.x*32 + tx;
#pragma unroll
  for (int jj = 0; jj < 4; jj++) {
    int r = blockIdx.y*32 + ty*4 + jj;
    tile[ty*4+jj][tx] = (k < IN_DIM) ? w[(size_t)r*IN_DIM + k] : 0.f;
  }
  __syncthreads();
#pragma unroll
  for (int jj = 0; jj < 4; jj++) {
    int kk = blockIdx.x*32 + ty*4 + jj;
    if (kk < IN_DIM) wT[(size_t)kk*G3 + blockIdx.y*32 + tx] = tile[tx][ty*4+jj];
  }
}

// ---- k2: IG0 = obs @ w_ih0^T + b_ih0 --------------------------------------
__global__ __launch_bounds__(256) void ig0_kernel(const float* __restrict__ wT,
                                                  const float* __restrict__ obs,
                                                  const float* __restrict__ b_ih0,
                                                  float* __restrict__ ig0) {
  int o = blockIdx.x*256 + threadIdx.x;
  int t0 = blockIdx.y * TTILE;
  float acc[TTILE];
  float b = b_ih0[o];
#pragma unroll
  for (int tt = 0; tt < TTILE; tt++) acc[tt] = b;
  for (int k = 0; k < IN_DIM; k++) {
    float wv = wT[(size_t)k*G3 + o];
#pragma unroll
    for (int tt = 0; tt < TTILE; tt++)
      acc[tt] = fmaf(obs[(size_t)(t0+tt)*IN_DIM + k], wv, acc[tt]);
  }
#pragma unroll
  for (int tt = 0; tt < TTILE; tt++)
    ig0[(size_t)(t0+tt)*G3 + o] = acc[tt];
}

// ---- k_init: seed ring slot 0 with tagged initial hidden -------------------
__global__ __launch_bounds__(512) void init_kernel(const float* __restrict__ hid,
                                                   unsigned long long* ring0,
                                                   unsigned long long* ring1) {
  int e = threadIdx.x;
  st_rlx64(&ring0[e], pack_tv(0u, hid[e]));
  st_rlx64(&ring1[e], pack_tv(0u, hid[HID + e]));
}

// ---- k3: fused sequential GRU scan ----------------------------------------
// 128 WGs x 192 threads, 1 WG/CU, 1 wave/EU -> 512-VGPR budget, weights
// pinned resident. Iteration k (0..T): stage h0[k-1] (ring0 slot k&15 tag k)
// and h1[k-2] (ring1 slot (k-1)&15 tag k-1); compute h0[k] (tid<64, k<T) and
// h1[k-1] (tid>=64, k>=1); publish h0[k] -> slot (k+1)&15 tag k+1 and
// h1[k-1] -> slot k&15 tag k.
__global__ __launch_bounds__(192)
__attribute__((amdgpu_waves_per_eu(1, 1)))
void seq_kernel(
    const float* __restrict__ ig0, const float* __restrict__ w_hh0,
    const float* __restrict__ b_n0, const float* __restrict__ w_ih1,
    const float* __restrict__ w_hh1, const float* __restrict__ b_ih1,
    const float* __restrict__ b_n1,
    unsigned long long* ring0, unsigned long long* ring1,
    float* __restrict__ h1a, float* __restrict__ d_out) {
  __shared__ float hbuf0[2][HID];
  __shared__ float hbuf1[2][HID];
  __shared__ float igbuf[2][12];
  __shared__ float vpad[24576];   // 96KB: occupancy calc -> 1 block/CU
  const int tid = threadIdx.x;
  const int wg = blockIdx.x;
  if (d_out == nullptr) {         // never true; defeats LDS elision
    vpad[tid] = (float)tid;
    __syncthreads();
    h1a[tid] = vpad[191 - tid];
  }

  const bool roleA = (tid < 64);           // 4 h0 elements, 16 lanes each
  const int u = tid - 64;                  // role B: 4 h1 elements, 32 lanes
  const int g = roleA ? (tid >> 4) : (u >> 5);    // 0..3
  const int jj = roleA ? (tid & 15) : (u & 15);
  const int half = roleA ? 0 : ((u >> 4) & 1);    // B: 0=ih(h0), 1=hh(h1)
  const int j32 = u & 31;
  const int eg = wg*4 + g;
  const bool leadA = roleA && (jj == 0);
  const bool leadB = (!roleA) && (j32 == 0);

  // 24 float4 (96 floats) of weights per lane, loaded once, PINNED resident.
  const float* wsrc = roleA ? w_hh0 : (half ? w_hh1 : w_ih1);
  float4 W[24];
#pragma unroll
  for (int gate = 0; gate < 3; gate++) {
    const float4* row = (const float4*)(wsrc + (size_t)(gate*HID + eg)*HID);
#pragma unroll
    for (int i = 0; i < 8; i++) {
      W[gate*8+i] = row[jj + 16*i];
      pin4(W[gate*8+i]);
    }
  }
  float cr=0.f, cz=0.f, cn=0.f, bnl;
  if (roleA) {
    bnl = b_n0[eg];
  } else {
    cr = b_ih1[eg]; cz = b_ih1[512+eg]; cn = b_ih1[1024+eg]; bnl = b_n1[eg];
  }

  const int iggate = tid >> 2, ige = tid & 3;   // tid<12: ig prefetch lanes
  if (tid < 12) igbuf[0][tid] = ig0[(size_t)iggate*HID + wg*4 + ige];

  for (int k = 0; k <= T_STEPS; k++) {
    const int p = k & 1;
    float igpre = 0.f;
    if (tid < 12) {
      int kk = (k+1 < T_STEPS) ? (k+1) : (T_STEPS-1);
      igpre = ig0[(size_t)kk*G3 + (size_t)iggate*HID + wg*4 + ige];
    }
    // ---- staging: batched 16B loads, per-8B-half tag verify ----
    const unsigned wk0 = (unsigned)k, wk1 = (unsigned)(k-1);
    if (k == 0) {
      const unsigned long long* s0 = ring0;   // slot 0, tag 0
      if (tid < 64) {
        v4u a, b;
        ld16x2(s0 + 2*tid, s0 + 2*(tid+192), a, b);
        vfy(a, s0 + 2*tid, wk0); vfy(b, s0 + 2*(tid+192), wk0);
        ((float2*)hbuf0[p])[tid]     = pairval(a);
        ((float2*)hbuf0[p])[tid+192] = pairval(b);
      } else {
        v4u a = ld16(s0 + 2*tid);
        vfy(a, s0 + 2*tid, wk0);
        ((float2*)hbuf0[p])[tid] = pairval(a);
      }
    } else {
      const unsigned long long* s0 = ring0 + (size_t)(k & R0M)*HID;
      const unsigned long long* s1 = ring1 + (size_t)((k-1) & R1M)*HID;
      if (tid < 64) {
        v4u a, b, c;
        ld16x3(s0 + 2*tid, s0 + 2*(tid+192), s1 + 2*tid, a, b, c);
        vfy(a, s0 + 2*tid, wk0); vfy(b, s0 + 2*(tid+192), wk0);
        vfy(c, s1 + 2*tid, wk1);
        ((float2*)hbuf0[p])[tid]     = pairval(a);
        ((float2*)hbuf0[p])[tid+192] = pairval(b);
        ((float2*)hbuf1[p])[tid]     = pairval(c);
      } else if (tid < 128) {
        v4u a, b, c;
        ld16x3(s0 + 2*tid, s1 + 2*tid, s1 + 2*(tid+128), a, b, c);
        vfy(a, s0 + 2*tid, wk0);
        vfy(b, s1 + 2*tid, wk1); vfy(c, s1 + 2*(tid+128), wk1);
        ((float2*)hbuf0[p])[tid]     = pairval(a);
        ((float2*)hbuf1[p])[tid]     = pairval(b);
        ((float2*)hbuf1[p])[tid+128] = pairval(c);
      } else {
        v4u a, b;
        ld16x2(s0 + 2*tid, s1 + 2*tid, a, b);
        vfy(a, s0 + 2*tid, wk0); vfy(b, s1 + 2*tid, wk1);
        ((float2*)hbuf0[p])[tid] = pairval(a);
        ((float2*)hbuf1[p])[tid] = pairval(b);
      }
    }
    __syncthreads();   // the only barrier per iteration
    // ---- compute ----
    const bool act = roleA ? (k < T_STEPS) : (k >= 1);
    if (act) {
      const float4* hp = (roleA || half == 0) ? (const float4*)hbuf0[p]
                                              : (const float4*)hbuf1[p];
      float pr=0.f, pz=0.f, pn=0.f;
#pragma unroll
      for (int i = 0; i < 8; i++) {
        float4 hv = hp[jj + 16*i];   // words 4jj+64i: conflict-free (<=2-way)
        pr += dot4(W[i],hv); pz += dot4(W[8+i],hv); pn += dot4(W[16+i],hv);
      }
#pragma unroll
      for (int s = 1; s < 16; s <<= 1) {
        pr += __shfl_xor(pr, s, 16);
        pz += __shfl_xor(pz, s, 16);
        pn += __shfl_xor(pn, s, 16);
      }
      if (roleA) {
        if (leadA) {
          float r = fast_sigmoid(igbuf[p][g] + pr);
          float z = fast_sigmoid(igbuf[p][4+g] + pz);
          float n = fast_tanh(igbuf[p][8+g] + r*(pn + bnl));
          float hnew = n + z*(hbuf0[p][eg] - n);
          st_rlx64(&ring0[(size_t)((k+1) & R0M)*HID + eg],
                   pack_tv((unsigned)(k+1), hnew));
          if (k == T_STEPS-1) d_out[T_STEPS + eg] = hnew;
        }
      } else {
        float qr = __shfl(pr, 16, 32);   // harvest hh-half sums
        float qz = __shfl(pz, 16, 32);
        float qn = __shfl(pn, 16, 32);
        if (leadB) {
          float r = fast_sigmoid(pr + cr + qr);
          float z = fast_sigmoid(pz + cz + qz);
          float n = fast_tanh(pn + cn + r*(qn + bnl));
          float hnew = n + z*(hbuf1[p][eg] - n);
          st_rlx64(&ring1[(size_t)(k & R1M)*HID + eg],
                   pack_tv((unsigned)k, hnew));
          h1a[(size_t)(k-1)*HID + eg] = hnew;   // plain store for the MLP
          if (k == T_STEPS) d_out[T_STEPS + HID + eg] = hnew;
        }
      }
    }
    if (tid < 12) igbuf[p ^ 1][tid] = igpre;
  }
}

// ---- k4: batched MLP head --------------------------------------------------
__global__ __launch_bounds__(64) void mlp_kernel(
    const float* __restrict__ h1_all, const float* __restrict__ mw0,
    const float* __restrict__ mb0, const float* __restrict__ mw1,
    const float* __restrict__ mb1, const float* __restrict__ mw2,
    const float* __restrict__ mb2, float* __restrict__ out) {
  const int l = threadIdx.x;
  const int t0 = blockIdx.x * 8;
  __shared__ float v0s[8][64];
  float acc[8];
#pragma unroll
  for (int tt = 0; tt < 8; tt++) acc[tt] = mb0[l];
  const float4* w = (const float4*)(mw0 + (size_t)l*512);
#pragma unroll 4
  for (int i = 0; i < 128; i++) {
    float4 a = w[i];
#pragma unroll
    for (int tt = 0; tt < 8; tt++) {
      float4 b = ((const float4*)(h1_all + (size_t)(t0+tt)*512))[i];
      acc[tt] = fmaf(a.x,b.x, fmaf(a.y,b.y, fmaf(a.z,b.z, fmaf(a.w,b.w, acc[tt]))));
    }
  }
#pragma unroll
  for (int tt = 0; tt < 8; tt++) v0s[tt][l] = fmaxf(acc[tt], 0.f);
  __syncthreads();
  float acc1[8];
#pragma unroll
  for (int tt = 0; tt < 8; tt++) acc1[tt] = mb1[l];
  const float* w1 = mw1 + (size_t)l*64;
  for (int jj = 0; jj < 64; jj++) {
    float wv = w1[jj];
#pragma unroll
    for (int tt = 0; tt < 8; tt++) acc1[tt] = fmaf(wv, v0s[tt][jj], acc1[tt]);
  }
  float w2 = mw2[l];
  float bb = mb2[0];
#pragma unroll
  for (int tt = 0; tt < 8; tt++) {
    float y = w2 * fmaxf(acc1[tt], 0.f);
#pragma unroll
    for (int s = 32; s > 0; s >>= 1) y += __shfl_down(y, s, 64);
    if (l == 0) out[t0+tt] = y + bb;
  }
}

// ---------------------------------------------------------------------------
extern "C" void kernel_launch(void* const* d_in, const int* in_sizes, int n_in,
                              void* d_out, int out_size, void* d_ws, size_t ws_size,
                              hipStream_t stream) {
  const float* p0  = (const float*)d_in[0];
  const float* p1  = (const float*)d_in[1];
  const float* p2  = (const float*)d_in[2];
  const float* p3  = (const float*)d_in[3];
  const float* p4  = (const float*)d_in[4];
  const float* p5  = (const float*)d_in[5];
  const float* p6  = (const float*)d_in[6];
  const float* p7  = (const float*)d_in[7];
  const float* p8  = (const float*)d_in[8];
  const float* p9  = (const float*)d_in[9];
  const float* p10 = (const float*)d_in[10];
  const float* p11 = (const float*)d_in[11];
  const float* p12 = (const float*)d_in[12];
  const float* hid   = (const float*)d_in[13];
  const float* w_ih0 = (const float*)d_in[14];
  const float* w_hh0 = (const float*)d_in[15];
  const float* b_ih0 = (const float*)d_in[16];
  const float* b_n0  = (const float*)d_in[17];
  const float* w_ih1 = (const float*)d_in[18];
  const float* w_hh1 = (const float*)d_in[19];
  const float* b_ih1 = (const float*)d_in[20];
  const float* b_n1  = (const float*)d_in[21];
  const float* mw0 = (const float*)d_in[22];
  const float* mb0 = (const float*)d_in[23];
  const float* mw1 = (const float*)d_in[24];
  const float* mb1 = (const float*)d_in[25];
  const float* mw2 = (const float*)d_in[26];
  const float* mb2 = (const float*)d_in[27];
  float* out = (float*)d_out;

  // workspace: ig0 | ring0 | ring1 | h1a  (obs/wT alias h1a region)
  char* base = (char*)d_ws;
  const size_t IG0_B = (size_t)T_STEPS*G3*4;     // 100,663,296
  const size_t R0_B  = (size_t)R0*HID*8;         //      65,536
  const size_t R1_B  = (size_t)R1*HID*8;         //      65,536
  const size_t H1A_B = (size_t)T_STEPS*HID*4;    //  33,554,432
  float* ig0 = (float*)base;
  unsigned long long* ring0 = (unsigned long long*)(base + IG0_B);
  unsigned long long* ring1 = (unsigned long long*)(base + IG0_B + R0_B);
  float* h1a = (float*)(base + IG0_B + R0_B + R1_B);
  float* obs = h1a;                                              // alias
  float* wT  = (float*)((char*)h1a + (size_t)T_STEPS*IN_DIM*4);  // alias
  if (ws_size < IG0_B + R0_B + R1_B + H1A_B) return;

  concat_kernel<<<T_STEPS, 384, 0, stream>>>(p0,p1,p2,p3,p4,p5,p6,p7,p8,p9,p10,p11,p12, obs);
  transpose_kernel<<<dim3(11,48), dim3(32,8), 0, stream>>>(w_ih0, wT);
  ig0_kernel<<<dim3(6, T_STEPS/TTILE), 256, 0, stream>>>(wT, obs, b_ih0, ig0);
  init_kernel<<<1, 512, 0, stream>>>(hid, ring0, ring1);
  seq_kernel<<<128, 192, 0, stream>>>(ig0, w_hh0, b_n0, w_ih1, w_hh1, b_ih1, b_n1,
                                      ring0, ring1, h1a, out);
  mlp_kernel<<<T_STEPS/8, 64, 0, stream>>>(h1a, mw0, mb0, mw1, mb1, mw2, mb2, out);
}